// Round 1
// baseline (14.939 us; speedup 1.0000x reference)
//
#include <hip/hip_runtime.h>

#define CANVAS 512
#define NPTS 64
#define NSEG (NPTS - 1)

__global__ __launch_bounds__(256) void diff_path_render(
    const float* __restrict__ traj,      // (64,2) normalized
    const float* __restrict__ thickness, // scalar
    float* __restrict__ out)             // (512,512)
{
    __shared__ float vx[NSEG], vy[NSEG], sx[NSEG], sy[NSEG], inv[NSEG];

    const int tid = threadIdx.x;
    if (tid < NSEG) {
        float ax = traj[2 * tid + 0] * (float)CANVAS;
        float ay = traj[2 * tid + 1] * (float)CANVAS;
        float bx = traj[2 * tid + 2] * (float)CANVAS;
        float by = traj[2 * tid + 3] * (float)CANVAS;
        float dx = bx - ax, dy = by - ay;
        vx[tid] = ax;
        vy[tid] = ay;
        sx[tid] = dx;
        sy[tid] = dy;
        inv[tid] = 1.0f / (dx * dx + dy * dy + 1e-5f);
    }
    __syncthreads();

    const int idx = blockIdx.x * blockDim.x + tid;  // flat pixel index
    const int row = idx >> 9;                       // i
    const int col = idx & (CANVAS - 1);             // j
    const float px = (float)col;                    // p = (col, row)
    const float py = (float)row;

    float mind2 = 1e30f;
#pragma unroll 9
    for (int s = 0; s < NSEG; ++s) {
        float dx = px - vx[s];
        float dy = py - vy[s];
        float t = (dx * sx[s] + dy * sy[s]) * inv[s];
        t = fminf(fmaxf(t, 0.0f), 1.0f);
        float qx = dx - t * sx[s];
        float qy = dy - t * sy[s];
        float d2 = qx * qx + qy * qy;
        mind2 = fminf(mind2, d2);
    }

    const float dist = sqrtf(mind2);
    const float radius = thickness[0] * 0.5f;
    const float darkness = fminf(fmaxf((radius - dist) / radius, 0.0f), 1.0f);
    out[idx] = darkness;
}

extern "C" void kernel_launch(void* const* d_in, const int* in_sizes, int n_in,
                              void* d_out, int out_size, void* d_ws, size_t ws_size,
                              hipStream_t stream) {
    const float* traj = (const float*)d_in[0];
    const float* thickness = (const float*)d_in[1];
    float* out = (float*)d_out;

    const int total = CANVAS * CANVAS;  // 262144
    const int block = 256;
    const int grid = total / block;     // 1024
    diff_path_render<<<grid, block, 0, stream>>>(traj, thickness, out);
}

// Round 2
// 11.513 us; speedup vs baseline: 1.2976x; 1.2976x over previous
//
#include <hip/hip_runtime.h>

#define CANVAS 512
#define NPTS 64
#define NSEG (NPTS - 1)

__global__ __launch_bounds__(256) void diff_path_render(
    const float* __restrict__ traj,      // (64,2) normalized
    const float* __restrict__ thickness, // scalar
    float* __restrict__ out)             // (512,512)
{
    const int t = blockIdx.x * blockDim.x + threadIdx.x;   // 0..131071
    const int pix0 = t * 2;              // two consecutive pixels in one row
    const int row = pix0 >> 9;
    const int col0 = pix0 & (CANVAS - 1);

    const float INV_S = 1.0f / 512.0f;
    const float py  = (float)row  * INV_S;
    const float px0 = (float)col0 * INV_S;
    const float px1 = px0 + INV_S;
    // reference adds 1e-5 to d2 in PIXEL units; normalized units scale by 512^2
    const float EPS = 1e-5f / (512.0f * 512.0f);

    float m0 = 1e30f, m1 = 1e30f;

    // rolling segment start (uniform scalar values)
    float ax = traj[0], ay = traj[1];
#pragma unroll 9
    for (int s = 0; s < NSEG; ++s) {
        float bx = traj[2 * s + 2];
        float by = traj[2 * s + 3];
        float segx = bx - ax, segy = by - ay;
        float d2  = fmaf(segx, segx, fmaf(segy, segy, EPS));
        float inv = __builtin_amdgcn_rcpf(d2);

        float dy  = py  - ay;
        float dx0 = px0 - ax;
        float dx1 = px1 - ax;
        float dysy = dy * segy;

        float t0 = fmaf(dx0, segx, dysy) * inv;
        float t1 = fmaf(dx1, segx, dysy) * inv;
        t0 = fminf(fmaxf(t0, 0.0f), 1.0f);   // v_med3_f32
        t1 = fminf(fmaxf(t1, 0.0f), 1.0f);

        float qx0 = fmaf(-t0, segx, dx0);
        float qy0 = fmaf(-t0, segy, dy);
        float qx1 = fmaf(-t1, segx, dx1);
        float qy1 = fmaf(-t1, segy, dy);

        float dd0 = fmaf(qx0, qx0, qy0 * qy0);
        float dd1 = fmaf(qx1, qx1, qy1 * qy1);
        m0 = fminf(m0, dd0);
        m1 = fminf(m1, dd1);

        ax = bx; ay = by;
    }

    const float radius = thickness[0] * 0.5f;
    const float rinv = __builtin_amdgcn_rcpf(radius);
    const float d0 = 512.0f * sqrtf(m0);
    const float d1 = 512.0f * sqrtf(m1);
    const float o0 = fminf(fmaxf((radius - d0) * rinv, 0.0f), 1.0f);
    const float o1 = fminf(fmaxf((radius - d1) * rinv, 0.0f), 1.0f);

    *reinterpret_cast<float2*>(out + pix0) = make_float2(o0, o1);
}

extern "C" void kernel_launch(void* const* d_in, const int* in_sizes, int n_in,
                              void* d_out, int out_size, void* d_ws, size_t ws_size,
                              hipStream_t stream) {
    const float* traj      = (const float*)d_in[0];
    const float* thickness = (const float*)d_in[1];
    float* out = (float*)d_out;

    const int threads = CANVAS * CANVAS / 2;  // 131072 threads, 2 px each
    const int block = 256;
    const int grid = threads / block;         // 512 blocks -> 2 waves/SIMD
    diff_path_render<<<grid, block, 0, stream>>>(traj, thickness, out);
}

// Round 3
// 11.186 us; speedup vs baseline: 1.3355x; 1.0292x over previous
//
#include <hip/hip_runtime.h>

#define CANVAS 512
#define NPTS 64
#define NSEG (NPTS - 1)

typedef float f2 __attribute__((ext_vector_type(2)));

__global__ __launch_bounds__(256) void diff_path_render(
    const float* __restrict__ traj,      // (64,2) normalized
    const float* __restrict__ thickness, // scalar
    float* __restrict__ out)             // (512,512)
{
    const int t = blockIdx.x * blockDim.x + threadIdx.x;   // 0..65535
    const int pix0 = t * 4;              // four consecutive pixels, one row
    const int row  = pix0 >> 9;
    const int col0 = pix0 & (CANVAS - 1);

    const float INV_S = 1.0f / 512.0f;
    const float py = (float)row * INV_S;
    const f2 px01 = { (float)(col0 + 0) * INV_S, (float)(col0 + 1) * INV_S };
    const f2 px23 = { (float)(col0 + 2) * INV_S, (float)(col0 + 3) * INV_S };
    // reference adds 1e-5 to d2 in PIXEL units; normalized units scale by 512^2
    const float EPS = 1e-5f / (512.0f * 512.0f);

    f2 m01 = { 1e30f, 1e30f };
    f2 m23 = { 1e30f, 1e30f };

    float ax = traj[0], ay = traj[1];    // wave-uniform rolling segment start
#pragma unroll 9
    for (int s = 0; s < NSEG; ++s) {
        float bx = traj[2 * s + 2];
        float by = traj[2 * s + 3];
        float segx = bx - ax, segy = by - ay;
        float d2  = fmaf(segx, segx, fmaf(segy, segy, EPS));
        float inv = __builtin_amdgcn_rcpf(d2);

        float dy   = py - ay;            // per-thread (row) scalar
        float dysy = dy * segy;

        const f2 segxv = { segx, segx };
        const f2 segyv = { segy, segy };
        const f2 dysyv = { dysy, dysy };
        const f2 axv   = { ax, ax };
        const f2 invv  = { inv, inv };
        const f2 zero  = { 0.0f, 0.0f };
        const f2 one   = { 1.0f, 1.0f };

        f2 dx01 = px01 - axv;                                    // v_pk_add
        f2 dx23 = px23 - axv;
        f2 t01 = __builtin_elementwise_fma(dx01, segxv, dysyv);  // v_pk_fma
        f2 t23 = __builtin_elementwise_fma(dx23, segxv, dysyv);
        t01 = t01 * invv;                                        // v_pk_mul
        t23 = t23 * invv;
        t01 = __builtin_elementwise_min(__builtin_elementwise_max(t01, zero), one);
        t23 = __builtin_elementwise_min(__builtin_elementwise_max(t23, zero), one);

        f2 qx01 = __builtin_elementwise_fma(-t01, segxv, dx01);
        f2 qx23 = __builtin_elementwise_fma(-t23, segxv, dx23);
        f2 dyv  = { dy, dy };
        f2 qy01 = __builtin_elementwise_fma(-t01, segyv, dyv);
        f2 qy23 = __builtin_elementwise_fma(-t23, segyv, dyv);

        f2 dd01 = __builtin_elementwise_fma(qx01, qx01, qy01 * qy01);
        f2 dd23 = __builtin_elementwise_fma(qx23, qx23, qy23 * qy23);
        m01 = __builtin_elementwise_min(m01, dd01);
        m23 = __builtin_elementwise_min(m23, dd23);

        ax = bx; ay = by;
    }

    const float radius = thickness[0] * 0.5f;
    const float rinv = __builtin_amdgcn_rcpf(radius);

    float4 o;
    o.x = fminf(fmaxf((radius - 512.0f * sqrtf(m01.x)) * rinv, 0.0f), 1.0f);
    o.y = fminf(fmaxf((radius - 512.0f * sqrtf(m01.y)) * rinv, 0.0f), 1.0f);
    o.z = fminf(fmaxf((radius - 512.0f * sqrtf(m23.x)) * rinv, 0.0f), 1.0f);
    o.w = fminf(fmaxf((radius - 512.0f * sqrtf(m23.y)) * rinv, 0.0f), 1.0f);

    *reinterpret_cast<float4*>(out + pix0) = o;
}

extern "C" void kernel_launch(void* const* d_in, const int* in_sizes, int n_in,
                              void* d_out, int out_size, void* d_ws, size_t ws_size,
                              hipStream_t stream) {
    const float* traj      = (const float*)d_in[0];
    const float* thickness = (const float*)d_in[1];
    float* out = (float*)d_out;

    const int threads = CANVAS * CANVAS / 4;  // 65536 threads, 4 px each
    const int block = 256;
    const int grid = threads / block;         // 256 blocks
    diff_path_render<<<grid, block, 0, stream>>>(traj, thickness, out);
}